// Round 13
// baseline (234.451 us; speedup 1.0000x reference)
//
#include <hip/hip_runtime.h>
#include <cmath>

typedef __bf16 bf16;
typedef bf16 bf16x4 __attribute__((ext_vector_type(4)));
typedef bf16 bf16x8 __attribute__((ext_vector_type(8)));
typedef float f32x4 __attribute__((ext_vector_type(4)));

#define MFMA16(a, b, c) __builtin_amdgcn_mfma_f32_16x16x32_bf16(a, b, c, 0, 0, 0)

// fp32 -> bf16 bulk convert of x (4Mi), Wqkv (3Mi), Wo (1Mi) in one launch.
__global__ __launch_bounds__(256) void cvt_all(
    const float* __restrict__ x, const float* __restrict__ wqkv,
    const float* __restrict__ wo, bf16* __restrict__ xb,
    bf16* __restrict__ wqkvb, bf16* __restrict__ wob) {
  int i = (blockIdx.x * 256 + threadIdx.x) * 4;
  const float* src;
  bf16* dst;
  if (i < (4 << 20)) {
    src = x + i; dst = xb + i;
  } else if (i < (7 << 20)) {
    src = wqkv + (i - (4 << 20)); dst = wqkvb + (i - (4 << 20));
  } else {
    src = wo + (i - (7 << 20)); dst = wob + (i - (7 << 20));
  }
  const f32x4 v = *(const f32x4*)src;
  bf16x4 o = {(bf16)v[0], (bf16)v[1], (bf16)v[2], (bf16)v[3]};
  *(bf16x4*)dst = o;
}

// C[m][n] = sum_k A[m][k] * Bm[n][k]   (NT GEMM, K=1024, M=4096)
// Tile 128 x BN.  Ping-pong LDS double buffer, one barrier/iter.
// EPI==1 (BN=128): A bf16; epilogue Q (RoPE, 1/8) / K (RoPE) / V^T.
// EPI==0 (BN=64):  A = O0+O1 bf16 split-K partials combined at staging and
//                  scaled by rcp(l0+l1); plain fp32 store.
template <int EPI, int BN>
__global__ __launch_bounds__(256) void gemm_nt(
    const bf16* __restrict__ A, const bf16* __restrict__ A2,
    const float* __restrict__ lacc, const bf16* __restrict__ Bm,
    const int* __restrict__ tokpos,
    bf16* __restrict__ out0, bf16* __restrict__ out1, bf16* __restrict__ out2,
    float* __restrict__ outF, int N) {
  constexpr int NI = BN / 32;
  __shared__ __align__(16) bf16 As[2][128 * 32];
  __shared__ __align__(16) bf16 Bs[2][BN * 32];
  const int tid = threadIdx.x;
  const int w = tid >> 6, lane = tid & 63, quad = lane >> 4, m16 = lane & 15;
  const int m0 = blockIdx.y * 128, n0 = blockIdx.x * BN;
  const int wm = (w >> 1) * 64, wn = (w & 1) * (BN / 2);

  f32x4 acc[4][NI] = {};

  const int row0 = tid >> 2, ch = tid & 3;
  const bf16* Ag0 = A + (size_t)(m0 + row0) * 1024 + ch * 8;
  const bf16* Ag1 = A + (size_t)(m0 + 64 + row0) * 1024 + ch * 8;
  const bf16* Cg0 = (EPI == 0) ? A2 + (size_t)(m0 + row0) * 1024 + ch * 8 : nullptr;
  const bf16* Cg1 = (EPI == 0) ? A2 + (size_t)(m0 + 64 + row0) * 1024 + ch * 8 : nullptr;
  const bf16* Bg0 = Bm + (size_t)(n0 + row0) * 1024 + ch * 8;
  const bf16* Bg1 =
      (BN == 128) ? Bm + (size_t)(n0 + 64 + row0) * 1024 + ch * 8 : nullptr;

  bf16x8 ra0, ra1, rc0, rc1, rb0, rb1;
  float lv0 = 1.f, lv1 = 1.f;
  auto LOAD = [&](int k0) {
    ra0 = *(const bf16x8*)(Ag0 + k0);
    ra1 = *(const bf16x8*)(Ag1 + k0);
    if constexpr (EPI == 0) {
      rc0 = *(const bf16x8*)(Cg0 + k0);
      rc1 = *(const bf16x8*)(Cg1 + k0);
      int h2 = ((k0 + ch * 8) >> 6) * 2;
      lv0 = lacc[(m0 + row0) * 32 + h2] + lacc[(m0 + row0) * 32 + h2 + 1];
      lv1 = lacc[(m0 + 64 + row0) * 32 + h2] +
            lacc[(m0 + 64 + row0) * 32 + h2 + 1];
    }
    rb0 = *(const bf16x8*)(Bg0 + k0);
    if constexpr (BN == 128) rb1 = *(const bf16x8*)(Bg1 + k0);
  };
  auto WRITE = [&](int p) {
    if constexpr (EPI == 0) {
      float i0 = 1.f / lv0, i1 = 1.f / lv1;
      bf16x8 w0, w1;
#pragma unroll
      for (int t = 0; t < 8; ++t) {
        w0[t] = (bf16)(((float)ra0[t] + (float)rc0[t]) * i0);
        w1[t] = (bf16)(((float)ra1[t] + (float)rc1[t]) * i1);
      }
      *(bf16x8*)(As[p] + tid * 8) = w0;
      *(bf16x8*)(As[p] + 2048 + tid * 8) = w1;
    } else {
      *(bf16x8*)(As[p] + tid * 8) = ra0;
      *(bf16x8*)(As[p] + 2048 + tid * 8) = ra1;
    }
    *(bf16x8*)(Bs[p] + tid * 8) = rb0;
    if constexpr (BN == 128) *(bf16x8*)(Bs[p] + 2048 + tid * 8) = rb1;
  };

  LOAD(0);
  WRITE(0);
  __syncthreads();

  int p = 0;
  for (int k0 = 0; k0 < 1024; k0 += 32) {
    const bool more = (k0 + 32) < 1024;
    if (more) LOAD(k0 + 32);
    bf16x8 af[4], bfr[NI];
#pragma unroll
    for (int mi = 0; mi < 4; ++mi)
      af[mi] = *(const bf16x8*)(As[p] + (wm + mi * 16 + m16) * 32 + quad * 8);
#pragma unroll
    for (int ni = 0; ni < NI; ++ni)
      bfr[ni] = *(const bf16x8*)(Bs[p] + (wn + ni * 16 + m16) * 32 + quad * 8);
#pragma unroll
    for (int mi = 0; mi < 4; ++mi)
#pragma unroll
      for (int ni = 0; ni < NI; ++ni)
        acc[mi][ni] = MFMA16(af[mi], bfr[ni], acc[mi][ni]);
    if (more) {
      WRITE(1 - p);
      __syncthreads();
      p ^= 1;
    }
  }

  if constexpr (EPI == 0) {
#pragma unroll
    for (int mi = 0; mi < 4; ++mi) {
      int rowb = m0 + wm + mi * 16 + quad * 4;
#pragma unroll
      for (int r = 0; r < 4; ++r) {
        size_t off = (size_t)(rowb + r) * N + n0 + wn;
#pragma unroll
        for (int ni = 0; ni < NI; ++ni)
          outF[off + ni * 16 + m16] = acc[mi][ni][r];
      }
    }
  } else {
#pragma unroll
    for (int mi = 0; mi < 4; ++mi) {
      int rowb = m0 + wm + mi * 16 + quad * 4;
      int pos4[4];
#pragma unroll
      for (int r = 0; r < 4; ++r) pos4[r] = tokpos[rowb + r];
#pragma unroll
      for (int ni = 0; ni < NI; ++ni) {
        int col = n0 + wn + ni * 16 + m16;
        int sec = col >> 10, f = col & 1023, h = f >> 6, d = f & 63;
        if (sec == 2) {
#pragma unroll
          for (int r = 0; r < 4; ++r) {
            int row = rowb + r;
            int bb = row >> 11, s = row & 2047;
            out2[((size_t)(bb * 16 + h) * 64 + d) * 2048 + s] =
                (bf16)acc[mi][ni][r];
          }
        } else {
          float inv = __expf(-(float)(d & ~1) * (9.2103403719762f / 64.f));
          bf16* dst = sec ? out1 : out0;
          const float sc = sec ? 1.0f : 0.125f;
#pragma unroll
          for (int r = 0; r < 4; ++r) {
            float v = acc[mi][ni][r];
            float vp = __shfl_xor(v, 1);
            float ang = (float)pos4[r] * inv;
            float cs, sn;
            __sincosf(ang, &sn, &cs);
            float ov = (d & 1) ? (v * cs + vp * sn) : (v * cs - vp * sn);
            ov *= sc;
            int row = rowb + r;
            int bb = row >> 11, s = row & 2047;
            dst[((size_t)(bb * 16 + h) * 2048 + s) * 64 + d] = (bf16)ov;
          }
        }
      }
    }
  }
}

// Split-K paired-q-tile causal flash attention, 1024 blocks for TLP:
// block = (bh, pair j, khalf); processes kt = khalf, khalf+2, ... <= qtB
// (fixed-shift softmax has no cross-kt dependency, so parity-split is exact).
// K tiles: LDS ping-pong (latency reservoir).  V fragments: straight from
// global (contiguous 16B in (bh,d,s)), issued at round start, consumed after
// QK+softmax -> latency hidden.  Partial O (bf16, unnormalized) and l (f32)
// per khalf; gemm0's A-staging combines and normalizes.
// LDS 27KB, lean registers -> 3-4 blocks/CU (was 2).
__global__ __launch_bounds__(256) void attn_kernel(
    const bf16* __restrict__ Q, const bf16* __restrict__ K,
    const bf16* __restrict__ Vt, bf16* __restrict__ O0,
    bf16* __restrict__ O1, float* __restrict__ lbuf) {
  __shared__ __align__(16) bf16 KP[2][64 * 72];  // K tiles, +8 row pad
  __shared__ __align__(16) bf16 PS[4][16 * 72];  // per-wave P strip
  const int tid = threadIdx.x;
  const int w = tid >> 6, lane = tid & 63, quad = lane >> 4, m16 = lane & 15;
  const int bh = blockIdx.x;
  const int wk = blockIdx.y;
  const int j = wk & 15, khalf = wk >> 4;
  const int qtA = j, qtB = 31 - j;
  const int q0A = qtA * 64, q0B = qtB * 64;
  const bf16* Qb = Q + (size_t)bh * 2048 * 64;
  const bf16* Kb = K + (size_t)bh * 2048 * 64;

  // K staging: thread covers K row `lane`, 16B chunks {w, w+4}
  const int ch0 = w * 8, ch1 = (w + 4) * 8;
  const bf16* Kg = Kb + (size_t)lane * 64;
  // V fragment base: contiguous 16B per fragment in (bh,d,s)
  const bf16* Vfrag = Vt + (size_t)bh * 64 * 2048 + m16 * 2048 + quad * 8;

  // Q strips in A-fragment layout (pre-scaled 1/8)
  const bf16* qrowA = Qb + (size_t)(q0A + w * 16 + m16) * 64;
  const bf16* qrowB = Qb + (size_t)(q0B + w * 16 + m16) * 64;
  bf16x8 aqA[2], aqB[2];
  aqA[0] = *(const bf16x8*)(qrowA + quad * 8);
  aqA[1] = *(const bf16x8*)(qrowA + 32 + quad * 8);
  aqB[0] = *(const bf16x8*)(qrowB + quad * 8);
  aqB[1] = *(const bf16x8*)(qrowB + 32 + quad * 8);

  bf16x8 rk0, rk1;
  auto PREFETCHK = [&](int kt) {
    rk0 = *(const bf16x8*)(Kg + (size_t)kt * 64 * 64 + ch0);
    rk1 = *(const bf16x8*)(Kg + (size_t)kt * 64 * 64 + ch1);
  };
  auto STAGE = [&](int p) {
    *(bf16x8*)(KP[p] + lane * 72 + ch0) = rk0;
    *(bf16x8*)(KP[p] + lane * 72 + ch1) = rk1;
  };

  PREFETCHK(khalf);
  STAGE(0);
  __syncthreads();

  f32x4 oA[4] = {}, oB[4] = {};
  float lA[4] = {0.f, 0.f, 0.f, 0.f}, lB[4] = {0.f, 0.f, 0.f, 0.f};
  const int qrel = w * 16 + quad * 4;

  int p = 0;
  for (int kt = khalf; kt <= qtB; kt += 2) {
    const bool more = (kt + 2) <= qtB;
    if (more) PREFETCHK(kt + 2);  // global->regs; waited only at STAGE

    // V fragments for this round: global loads issued up front,
    // first consumed after QK + softmax (~400 cyc) -> L2 latency hidden
    bf16x8 bv[2][4];
#pragma unroll
    for (int kk = 0; kk < 2; ++kk)
#pragma unroll
      for (int ng = 0; ng < 4; ++ng)
        bv[kk][ng] = *(const bf16x8*)(Vfrag + (size_t)ng * 16 * 2048 +
                                      kt * 64 + kk * 32);

    // one strip = QK (bk inline from LDS) + softmax + PV; strips sequential
    auto strip = [&](const bf16x8* aq, f32x4* o, float* lp, bool diag) {
      f32x4 sa[4] = {};
#pragma unroll
      for (int kk = 0; kk < 2; ++kk)
#pragma unroll
        for (int ni = 0; ni < 4; ++ni) {
          bf16x8 bk = *(const bf16x8*)(KP[p] + (ni * 16 + m16) * 72 +
                                       kk * 32 + quad * 8);
          sa[ni] = MFMA16(aq[kk], bk, sa[ni]);
        }
      bf16* ps = PS[w];
#pragma unroll
      for (int r = 0; r < 4; ++r) {
#pragma unroll
        for (int ni = 0; ni < 4; ++ni) {
          // p = exp(s-8) = exp2(s*log2e - 8*log2e)
          float pp = exp2f(fmaf(sa[ni][r], 1.44269504f, -11.5415603f));
          if (diag && (ni * 16 + m16) > qrel + r) pp = 0.f;
          lp[r] += pp;
          ps[(quad * 4 + r) * 72 + ni * 16 + m16] = (bf16)pp;
        }
      }
      // per-wave P strip: intra-wave LDS write->read ordering, no barrier
      bf16x8 ap[2];
      ap[0] = *(const bf16x8*)(ps + m16 * 72 + quad * 8);
      ap[1] = *(const bf16x8*)(ps + m16 * 72 + 32 + quad * 8);
#pragma unroll
      for (int kk = 0; kk < 2; ++kk)
#pragma unroll
        for (int ng = 0; ng < 4; ++ng)
          o[ng] = MFMA16(ap[kk], bv[kk][ng], o[ng]);
    };

    strip(aqB, oB, lB, kt == qtB);
    if (kt <= qtA) strip(aqA, oA, lA, kt == qtA);

    if (more) {
      STAGE(1 - p);      // idle buffer: no reader until after the barrier
      __syncthreads();   // single barrier per round
      p ^= 1;
    }
  }

  // epilogue: write UNNORMALIZED bf16 partial O + f32 partial l
  const int b = bh >> 4, h = bh & 15;
  bf16* Ob = khalf ? O1 : O0;
  auto epilogue = [&](f32x4* o, float* lp, int q0) {
#pragma unroll
    for (int r = 0; r < 4; ++r) {
      float l = lp[r];
      l += __shfl_xor(l, 1);
      l += __shfl_xor(l, 2);
      l += __shfl_xor(l, 4);
      l += __shfl_xor(l, 8);
      int s = q0 + w * 16 + quad * 4 + r;
      size_t rowoff = (size_t)(b * 2048 + s) * 1024 + h * 64;
#pragma unroll
      for (int ng = 0; ng < 4; ++ng)
        Ob[rowoff + ng * 16 + m16] = (bf16)o[ng][r];
      if (m16 == 0) lbuf[(size_t)(b * 2048 + s) * 32 + h * 2 + khalf] = l;
    }
  };
  epilogue(oA, lA, q0A);
  epilogue(oB, lB, q0B);
}

extern "C" void kernel_launch(void* const* d_in, const int* in_sizes, int n_in,
                              void* d_out, int out_size, void* d_ws, size_t ws_size,
                              hipStream_t stream) {
  (void)in_sizes; (void)n_in; (void)out_size; (void)ws_size;
  const float* x = (const float*)d_in[0];       // (2,2048,1024) fp32
  const float* Wqkv = (const float*)d_in[1];    // (3072,1024) fp32
  const float* Wo = (const float*)d_in[2];      // (1024,1024) fp32
  const int* tokpos = (const int*)d_in[3];      // (2,2048) int32
  float* out = (float*)d_out;                   // (2,2048,1024) fp32

  // workspace (42.5 MiB):
  //  [0,8)   Qws   [8,16) Kws   [16,24) Vtw
  //  [24,32) phase1: xb      | phase2: O0 (bf16 partial)
  //  [32,40) phase1: Wqkvb   | phase2: O1 (bf16 partial)
  //  [40,40.5) lbuf f32 (row*32 + h*2 + khalf)
  //  [40.5,42.5) Wob
  char* wsb = (char*)d_ws;
  bf16* Qws = (bf16*)wsb;
  bf16* Kws = (bf16*)(wsb + ((size_t)8 << 20));
  bf16* Vtw = (bf16*)(wsb + ((size_t)16 << 20));
  bf16* xb = (bf16*)(wsb + ((size_t)24 << 20));
  bf16* O0 = (bf16*)(wsb + ((size_t)24 << 20));
  bf16* Wqkvb = (bf16*)(wsb + ((size_t)32 << 20));
  bf16* O1 = (bf16*)(wsb + ((size_t)32 << 20));
  float* lbuf = (float*)(wsb + ((size_t)40 << 20));
  bf16* Wob = (bf16*)(wsb + ((size_t)40 << 20) + ((size_t)512 << 10));

  // 0) fp32 -> bf16 conversion of all inputs
  cvt_all<<<8192, 256, 0, stream>>>(x, Wqkv, Wo, xb, Wqkvb, Wob);

  // 1) QKV projection + RoPE + head-layout epilogue: M=4096, N=3072
  gemm_nt<1, 128><<<dim3(24, 32), 256, 0, stream>>>(
      xb, nullptr, nullptr, Wqkvb, tokpos, Qws, Kws, Vtw, nullptr, 3072);
  // 2) split-K paired-tile causal flash attention (1024 blocks)
  attn_kernel<<<dim3(32, 32), 256, 0, stream>>>(Qws, Kws, Vtw, O0, O1, lbuf);
  // 3) output projection with fused partial-combine + normalize
  gemm_nt<0, 64><<<dim3(16, 32), 256, 0, stream>>>(
      O0, O1, lbuf, Wob, nullptr, nullptr, nullptr, nullptr, out, 1024);
}

// Round 14
// 223.717 us; speedup vs baseline: 1.0480x; 1.0480x over previous
//
#include <hip/hip_runtime.h>
#include <cmath>

typedef __bf16 bf16;
typedef bf16 bf16x4 __attribute__((ext_vector_type(4)));
typedef bf16 bf16x8 __attribute__((ext_vector_type(8)));
typedef float f32x4 __attribute__((ext_vector_type(4)));

#define MFMA16(a, b, c) __builtin_amdgcn_mfma_f32_16x16x32_bf16(a, b, c, 0, 0, 0)

// fp32 -> bf16 bulk convert of x (4Mi), Wqkv (3Mi), Wo (1Mi) in one launch.
__global__ __launch_bounds__(256) void cvt_all(
    const float* __restrict__ x, const float* __restrict__ wqkv,
    const float* __restrict__ wo, bf16* __restrict__ xb,
    bf16* __restrict__ wqkvb, bf16* __restrict__ wob) {
  int i = (blockIdx.x * 256 + threadIdx.x) * 4;
  const float* src;
  bf16* dst;
  if (i < (4 << 20)) {
    src = x + i; dst = xb + i;
  } else if (i < (7 << 20)) {
    src = wqkv + (i - (4 << 20)); dst = wqkvb + (i - (4 << 20));
  } else {
    src = wo + (i - (7 << 20)); dst = wob + (i - (7 << 20));
  }
  const f32x4 v = *(const f32x4*)src;
  bf16x4 o = {(bf16)v[0], (bf16)v[1], (bf16)v[2], (bf16)v[3]};
  *(bf16x4*)dst = o;
}

// C[m][n] = sum_k A[m][k] * Bm[n][k]   (NT GEMM, K=1024, M=4096)
// Tile 128 x BN.  Ping-pong LDS double buffer, one barrier/iter.
// EPI==1 (BN=128): A bf16; epilogue Q (RoPE, 1/8) / K (RoPE) / V^T.
// EPI==0 (BN=64):  A = O0+O1 bf16 split-K partials combined at staging and
//                  scaled by rcp(l0+l1); plain fp32 store.
template <int EPI, int BN>
__global__ __launch_bounds__(256) void gemm_nt(
    const bf16* __restrict__ A, const bf16* __restrict__ A2,
    const float* __restrict__ lacc, const bf16* __restrict__ Bm,
    const int* __restrict__ tokpos,
    bf16* __restrict__ out0, bf16* __restrict__ out1, bf16* __restrict__ out2,
    float* __restrict__ outF, int N) {
  constexpr int NI = BN / 32;
  __shared__ __align__(16) bf16 As[2][128 * 32];
  __shared__ __align__(16) bf16 Bs[2][BN * 32];
  const int tid = threadIdx.x;
  const int w = tid >> 6, lane = tid & 63, quad = lane >> 4, m16 = lane & 15;
  const int m0 = blockIdx.y * 128, n0 = blockIdx.x * BN;
  const int wm = (w >> 1) * 64, wn = (w & 1) * (BN / 2);

  f32x4 acc[4][NI] = {};

  const int row0 = tid >> 2, ch = tid & 3;
  const bf16* Ag0 = A + (size_t)(m0 + row0) * 1024 + ch * 8;
  const bf16* Ag1 = A + (size_t)(m0 + 64 + row0) * 1024 + ch * 8;
  const bf16* Cg0 = (EPI == 0) ? A2 + (size_t)(m0 + row0) * 1024 + ch * 8 : nullptr;
  const bf16* Cg1 = (EPI == 0) ? A2 + (size_t)(m0 + 64 + row0) * 1024 + ch * 8 : nullptr;
  const bf16* Bg0 = Bm + (size_t)(n0 + row0) * 1024 + ch * 8;
  const bf16* Bg1 =
      (BN == 128) ? Bm + (size_t)(n0 + 64 + row0) * 1024 + ch * 8 : nullptr;

  bf16x8 ra0, ra1, rc0, rc1, rb0, rb1;
  float lv0 = 1.f, lv1 = 1.f;
  auto LOAD = [&](int k0) {
    ra0 = *(const bf16x8*)(Ag0 + k0);
    ra1 = *(const bf16x8*)(Ag1 + k0);
    if constexpr (EPI == 0) {
      rc0 = *(const bf16x8*)(Cg0 + k0);
      rc1 = *(const bf16x8*)(Cg1 + k0);
      int h2 = ((k0 + ch * 8) >> 6) * 2;
      lv0 = lacc[(m0 + row0) * 32 + h2] + lacc[(m0 + row0) * 32 + h2 + 1];
      lv1 = lacc[(m0 + 64 + row0) * 32 + h2] +
            lacc[(m0 + 64 + row0) * 32 + h2 + 1];
    }
    rb0 = *(const bf16x8*)(Bg0 + k0);
    if constexpr (BN == 128) rb1 = *(const bf16x8*)(Bg1 + k0);
  };
  auto WRITE = [&](int p) {
    if constexpr (EPI == 0) {
      float i0 = 1.f / lv0, i1 = 1.f / lv1;
      bf16x8 w0, w1;
#pragma unroll
      for (int t = 0; t < 8; ++t) {
        w0[t] = (bf16)(((float)ra0[t] + (float)rc0[t]) * i0);
        w1[t] = (bf16)(((float)ra1[t] + (float)rc1[t]) * i1);
      }
      *(bf16x8*)(As[p] + tid * 8) = w0;
      *(bf16x8*)(As[p] + 2048 + tid * 8) = w1;
    } else {
      *(bf16x8*)(As[p] + tid * 8) = ra0;
      *(bf16x8*)(As[p] + 2048 + tid * 8) = ra1;
    }
    *(bf16x8*)(Bs[p] + tid * 8) = rb0;
    if constexpr (BN == 128) *(bf16x8*)(Bs[p] + 2048 + tid * 8) = rb1;
  };

  LOAD(0);
  WRITE(0);
  __syncthreads();

  int p = 0;
  for (int k0 = 0; k0 < 1024; k0 += 32) {
    const bool more = (k0 + 32) < 1024;
    if (more) LOAD(k0 + 32);
    bf16x8 af[4], bfr[NI];
#pragma unroll
    for (int mi = 0; mi < 4; ++mi)
      af[mi] = *(const bf16x8*)(As[p] + (wm + mi * 16 + m16) * 32 + quad * 8);
#pragma unroll
    for (int ni = 0; ni < NI; ++ni)
      bfr[ni] = *(const bf16x8*)(Bs[p] + (wn + ni * 16 + m16) * 32 + quad * 8);
#pragma unroll
    for (int mi = 0; mi < 4; ++mi)
#pragma unroll
      for (int ni = 0; ni < NI; ++ni)
        acc[mi][ni] = MFMA16(af[mi], bfr[ni], acc[mi][ni]);
    if (more) {
      WRITE(1 - p);
      __syncthreads();
      p ^= 1;
    }
  }

  if constexpr (EPI == 0) {
#pragma unroll
    for (int mi = 0; mi < 4; ++mi) {
      int rowb = m0 + wm + mi * 16 + quad * 4;
#pragma unroll
      for (int r = 0; r < 4; ++r) {
        size_t off = (size_t)(rowb + r) * N + n0 + wn;
#pragma unroll
        for (int ni = 0; ni < NI; ++ni)
          outF[off + ni * 16 + m16] = acc[mi][ni][r];
      }
    }
  } else {
#pragma unroll
    for (int mi = 0; mi < 4; ++mi) {
      int rowb = m0 + wm + mi * 16 + quad * 4;
      int pos4[4];
#pragma unroll
      for (int r = 0; r < 4; ++r) pos4[r] = tokpos[rowb + r];
#pragma unroll
      for (int ni = 0; ni < NI; ++ni) {
        int col = n0 + wn + ni * 16 + m16;
        int sec = col >> 10, f = col & 1023, h = f >> 6, d = f & 63;
        if (sec == 2) {
#pragma unroll
          for (int r = 0; r < 4; ++r) {
            int row = rowb + r;
            int bb = row >> 11, s = row & 2047;
            out2[((size_t)(bb * 16 + h) * 64 + d) * 2048 + s] =
                (bf16)acc[mi][ni][r];
          }
        } else {
          float inv = __expf(-(float)(d & ~1) * (9.2103403719762f / 64.f));
          bf16* dst = sec ? out1 : out0;
          const float sc = sec ? 1.0f : 0.125f;
#pragma unroll
          for (int r = 0; r < 4; ++r) {
            float v = acc[mi][ni][r];
            float vp = __shfl_xor(v, 1);
            float ang = (float)pos4[r] * inv;
            float cs, sn;
            __sincosf(ang, &sn, &cs);
            float ov = (d & 1) ? (v * cs + vp * sn) : (v * cs - vp * sn);
            ov *= sc;
            int row = rowb + r;
            int bb = row >> 11, s = row & 2047;
            dst[((size_t)(bb * 16 + h) * 2048 + s) * 64 + d] = (bf16)ov;
          }
        }
      }
    }
  }
}

// Split-K paired-q-tile causal flash attention with FULL K+V LDS ping-pong
// (the R12 latency reservoir) and parity K-split for TLP:
// block = (bh, pair j, khalf) processes kt = khalf, khalf+2, ... <= qtB.
// LDS = KP[2]+VP[2]+PS[4] = 46 KB -> 3 blocks/CU; grid 1024 -> 12 waves/CU
// (R12 was 8).  Partial O (bf16, unnormalized) + l (f32) per khalf; gemm0's
// A-staging combines and normalizes.  Fixed-shift softmax p=exp(s-8).
__global__ __launch_bounds__(256) void attn_kernel(
    const bf16* __restrict__ Q, const bf16* __restrict__ K,
    const bf16* __restrict__ Vt, bf16* __restrict__ O0,
    bf16* __restrict__ O1, float* __restrict__ lbuf) {
  __shared__ __align__(16) bf16 KP[2][64 * 72];  // K tiles, +8 row pad
  __shared__ __align__(16) bf16 VP[2][64 * 72];  // V^T tiles, +8 row pad
  __shared__ __align__(16) bf16 PS[4][16 * 72];  // per-wave P strip (shared)
  const int tid = threadIdx.x;
  const int w = tid >> 6, lane = tid & 63, quad = lane >> 4, m16 = lane & 15;
  const int bh = blockIdx.x;
  const int wk = blockIdx.y;
  const int j = wk & 15, khalf = wk >> 4;
  const int qtA = j, qtB = 31 - j;
  const int q0A = qtA * 64, q0B = qtB * 64;
  const bf16* Qb = Q + (size_t)bh * 2048 * 64;
  const bf16* Kb = K + (size_t)bh * 2048 * 64;
  const bf16* Vb = Vt + (size_t)bh * 64 * 2048;

  // staging: thread covers K/V row `lane`, 16B chunks {w, w+4}
  const int ch0 = w * 8, ch1 = (w + 4) * 8;
  const bf16* Kg = Kb + (size_t)lane * 64;
  const bf16* Vg = Vb + (size_t)lane * 2048;

  // Q strips in A-fragment layout (pre-scaled 1/8)
  const bf16* qrowA = Qb + (size_t)(q0A + w * 16 + m16) * 64;
  const bf16* qrowB = Qb + (size_t)(q0B + w * 16 + m16) * 64;
  bf16x8 aqA[2], aqB[2];
  aqA[0] = *(const bf16x8*)(qrowA + quad * 8);
  aqA[1] = *(const bf16x8*)(qrowA + 32 + quad * 8);
  aqB[0] = *(const bf16x8*)(qrowB + quad * 8);
  aqB[1] = *(const bf16x8*)(qrowB + 32 + quad * 8);

  bf16x8 rk0, rk1, rv0, rv1;
  auto PREFETCH = [&](int kt) {
    rk0 = *(const bf16x8*)(Kg + (size_t)kt * 64 * 64 + ch0);
    rk1 = *(const bf16x8*)(Kg + (size_t)kt * 64 * 64 + ch1);
    rv0 = *(const bf16x8*)(Vg + kt * 64 + ch0);
    rv1 = *(const bf16x8*)(Vg + kt * 64 + ch1);
  };
  auto STAGE = [&](int p) {
    *(bf16x8*)(KP[p] + lane * 72 + ch0) = rk0;
    *(bf16x8*)(KP[p] + lane * 72 + ch1) = rk1;
    *(bf16x8*)(VP[p] + lane * 72 + ch0) = rv0;
    *(bf16x8*)(VP[p] + lane * 72 + ch1) = rv1;
  };

  PREFETCH(khalf);
  STAGE(0);
  __syncthreads();

  f32x4 oA[4] = {}, oB[4] = {};
  float lA[4] = {0.f, 0.f, 0.f, 0.f}, lB[4] = {0.f, 0.f, 0.f, 0.f};
  const int qrel = w * 16 + quad * 4;

  int p = 0;
  for (int kt = khalf; kt <= qtB; kt += 2) {
    const bool more = (kt + 2) <= qtB;
    if (more) PREFETCH(kt + 2);  // global->regs; waited only at STAGE

    // one strip = QK + softmax + PV (all operands LDS/register resident)
    auto strip = [&](const bf16x8* aq, f32x4* o, float* lp, bool diag) {
      f32x4 sa[4] = {};
#pragma unroll
      for (int kk = 0; kk < 2; ++kk)
#pragma unroll
        for (int ni = 0; ni < 4; ++ni) {
          bf16x8 bk = *(const bf16x8*)(KP[p] + (ni * 16 + m16) * 72 +
                                       kk * 32 + quad * 8);
          sa[ni] = MFMA16(aq[kk], bk, sa[ni]);
        }
      bf16* ps = PS[w];
#pragma unroll
      for (int r = 0; r < 4; ++r) {
#pragma unroll
        for (int ni = 0; ni < 4; ++ni) {
          // p = exp(s-8) = exp2(s*log2e - 8*log2e)
          float pp = exp2f(fmaf(sa[ni][r], 1.44269504f, -11.5415603f));
          if (diag && (ni * 16 + m16) > qrel + r) pp = 0.f;
          lp[r] += pp;
          ps[(quad * 4 + r) * 72 + ni * 16 + m16] = (bf16)pp;
        }
      }
      // per-wave P strip: intra-wave LDS write->read ordering, no barrier
      bf16x8 ap[2];
      ap[0] = *(const bf16x8*)(ps + m16 * 72 + quad * 8);
      ap[1] = *(const bf16x8*)(ps + m16 * 72 + 32 + quad * 8);
#pragma unroll
      for (int kk = 0; kk < 2; ++kk)
#pragma unroll
        for (int ng = 0; ng < 4; ++ng) {
          bf16x8 bv = *(const bf16x8*)(VP[p] + (ng * 16 + m16) * 72 +
                                       kk * 32 + quad * 8);
          o[ng] = MFMA16(ap[kk], bv, o[ng]);
        }
    };

    strip(aqB, oB, lB, kt == qtB);
    if (kt <= qtA) strip(aqA, oA, lA, kt == qtA);

    if (more) {
      STAGE(1 - p);      // idle buffer: no reader until after the barrier
      __syncthreads();   // single barrier per round
      p ^= 1;
    }
  }

  // epilogue: write UNNORMALIZED bf16 partial O + f32 partial l
  const int b = bh >> 4, h = bh & 15;
  bf16* Ob = khalf ? O1 : O0;
  auto epilogue = [&](f32x4* o, float* lp, int q0) {
#pragma unroll
    for (int r = 0; r < 4; ++r) {
      float l = lp[r];
      l += __shfl_xor(l, 1);
      l += __shfl_xor(l, 2);
      l += __shfl_xor(l, 4);
      l += __shfl_xor(l, 8);
      int s = q0 + w * 16 + quad * 4 + r;
      size_t rowoff = (size_t)(b * 2048 + s) * 1024 + h * 64;
#pragma unroll
      for (int ng = 0; ng < 4; ++ng)
        Ob[rowoff + ng * 16 + m16] = (bf16)o[ng][r];
      if (m16 == 0) lbuf[(size_t)(b * 2048 + s) * 32 + h * 2 + khalf] = l;
    }
  };
  epilogue(oA, lA, q0A);
  epilogue(oB, lB, q0B);
}

extern "C" void kernel_launch(void* const* d_in, const int* in_sizes, int n_in,
                              void* d_out, int out_size, void* d_ws, size_t ws_size,
                              hipStream_t stream) {
  (void)in_sizes; (void)n_in; (void)out_size; (void)ws_size;
  const float* x = (const float*)d_in[0];       // (2,2048,1024) fp32
  const float* Wqkv = (const float*)d_in[1];    // (3072,1024) fp32
  const float* Wo = (const float*)d_in[2];      // (1024,1024) fp32
  const int* tokpos = (const int*)d_in[3];      // (2,2048) int32
  float* out = (float*)d_out;                   // (2,2048,1024) fp32

  // workspace (42.5 MiB):
  //  [0,8)   Qws   [8,16) Kws   [16,24) Vtw
  //  [24,32) phase1: xb      | phase2: O0 (bf16 partial)
  //  [32,40) phase1: Wqkvb   | phase2: O1 (bf16 partial)
  //  [40,40.5) lbuf f32 (row*32 + h*2 + khalf)
  //  [40.5,42.5) Wob
  char* wsb = (char*)d_ws;
  bf16* Qws = (bf16*)wsb;
  bf16* Kws = (bf16*)(wsb + ((size_t)8 << 20));
  bf16* Vtw = (bf16*)(wsb + ((size_t)16 << 20));
  bf16* xb = (bf16*)(wsb + ((size_t)24 << 20));
  bf16* O0 = (bf16*)(wsb + ((size_t)24 << 20));
  bf16* Wqkvb = (bf16*)(wsb + ((size_t)32 << 20));
  bf16* O1 = (bf16*)(wsb + ((size_t)32 << 20));
  float* lbuf = (float*)(wsb + ((size_t)40 << 20));
  bf16* Wob = (bf16*)(wsb + ((size_t)40 << 20) + ((size_t)512 << 10));

  // 0) fp32 -> bf16 conversion of all inputs
  cvt_all<<<8192, 256, 0, stream>>>(x, Wqkv, Wo, xb, Wqkvb, Wob);

  // 1) QKV projection + RoPE + head-layout epilogue: M=4096, N=3072
  gemm_nt<1, 128><<<dim3(24, 32), 256, 0, stream>>>(
      xb, nullptr, nullptr, Wqkvb, tokpos, Qws, Kws, Vtw, nullptr, 3072);
  // 2) split-K paired-tile causal flash attention (1024 blocks, K+V in LDS)
  attn_kernel<<<dim3(32, 32), 256, 0, stream>>>(Qws, Kws, Vtw, O0, O1, lbuf);
  // 3) output projection with fused partial-combine + normalize
  gemm_nt<0, 64><<<dim3(16, 32), 256, 0, stream>>>(
      O0, O1, lbuf, Wob, nullptr, nullptr, nullptr, nullptr, out, 1024);
}